// Round 8
// baseline (167.508 us; speedup 1.0000x reference)
//
#include <hip/hip_runtime.h>

// ChannelAttention for MI355X (gfx950), round 7: barrier-free wave-private k1.
// B=4, L=16384, C=128, H=8, hd=16. Tokens M = 65536.
//
// R7 vs R6: k1's 60us was wave-convoying at the block barrier (occ 32%,
// VALUBusy 34% -> ~2.5 waves/SIMD effective). Now each wave is fully
// self-contained: 16 tokens x all 24 n-tiles (acc 96 VGPR), transpose into a
// wave-PRIVATE 12.5 KB LDS region, read own writes (lgkmcnt only, NO
// __syncthreads anywhere in k1). Waves desync and fill each other's stalls.
// __launch_bounds__(256,3): 170-reg cap fits the ~150 peak without spill.
//   k1 qkv_attn: qkv = x@Wqkv+b (MFMA) -> wave-private LDS transpose ->
//      per-(token,head) fp32 softmax-attention -> bf16 o to global.
//      o lives INSIDE d_out: first 256 B of each token's 512 B fp32 row.
//   k2 proj: out = o@Wproj+b. Streaming GEMM (R6, near HBM floor).
// Weights pre-transposed+bf16 in d_ws ([N][K] -> B-frags are 16B loads).

typedef __attribute__((ext_vector_type(8))) short bf16x8;
typedef __attribute__((ext_vector_type(4))) float f32x4;
typedef __attribute__((ext_vector_type(4))) unsigned int u32x4;

#define QKV_STRIDE 392   // bf16 elems per LDS token row (>=384); 784B, 16B aligned
#define WAVE_LDS (16 * QKV_STRIDE)   // 6272 elems = 12544 B per wave
#define PTILE 64         // k2 tokens per block
#define O_STRIDE 136     // k2 LDS row stride (bf16 elems)

__device__ __forceinline__ unsigned short f2bf(float f) {
    unsigned int u = __builtin_bit_cast(unsigned int, f);
    u += 0x8000u;                      // round half up
    return (unsigned short)(u >> 16);
}
// pack two floats -> packed bf16x2 (lo in low short) in 3 VALU ops
__device__ __forceinline__ unsigned int pkbf(float lo, float hi) {
    unsigned int a = __builtin_bit_cast(unsigned int, lo) + 0x8000u;
    unsigned int b = __builtin_bit_cast(unsigned int, hi) + 0x8000u;
    return __builtin_amdgcn_perm(b, a, 0x07060302u);  // {hi16(b),hi16(a)}
}
__device__ __forceinline__ float bflo(unsigned int u) {
    return __builtin_bit_cast(float, u << 16);
}
__device__ __forceinline__ float bfhi(unsigned int u) {
    return __builtin_bit_cast(float, u & 0xffff0000u);
}

__global__ void prep_weights(const float* __restrict__ wqkv,
                             const float* __restrict__ wproj,
                             unsigned short* __restrict__ wqkvT,
                             unsigned short* __restrict__ wprojT) {
    int idx = blockIdx.x * 256 + threadIdx.x;
    if (idx < 384 * 128) {               // wqkvT[n][k] = bf16(wqkv[k][n])
        int n = idx >> 7, k = idx & 127;
        wqkvT[idx] = f2bf(wqkv[k * 384 + n]);
    }
    if (idx < 128 * 128) {               // wprojT[n][k] = bf16(wproj[k][n])
        int n = idx >> 7, k = idx & 127;
        wprojT[idx] = f2bf(wproj[k * 128 + n]);
    }
}

// ---------------- kernel 1: qkv GEMM + channel attention (barrier-free) ----
__global__ __launch_bounds__(256, 3) void qkv_attn(
    const float* __restrict__ x,
    const unsigned short* __restrict__ wqkvT,
    const float* __restrict__ bqkv,
    char* __restrict__ obuf)          // = (char*)d_out; o row t at byte t*512
{
    __shared__ __align__(16) unsigned short us[4 * WAVE_LDS];  // 50176 B

    const int tid  = threadIdx.x;
    const int lane = tid & 63;
    const int wave = tid >> 6;
    const int col  = lane & 15;   // MFMA C/D col == A row (m) == B col (n)
    const int quad = lane >> 4;
    // wave-private: 16 tokens, private LDS region
    const long wbase = (long)blockIdx.x * 64 + wave * 16;
    unsigned short* uw = us + wave * WAVE_LDS;

    // ---- stage A: x fragments for this wave's 16 tokens (8 loads in flight)
    const float* xrow = x + (wbase + col) * 128;
    float4 s[4][2];
#pragma unroll
    for (int ks = 0; ks < 4; ++ks) {
        const float4* p = (const float4*)(xrow + ks * 32 + quad * 8);
        s[ks][0] = p[0];
        s[ks][1] = p[1];
    }
    bf16x8 afr[4];
#pragma unroll
    for (int ks = 0; ks < 4; ++ks) {
        float4 f0 = s[ks][0], f1 = s[ks][1];
        u32x4 a = {pkbf(f0.x, f0.y), pkbf(f0.z, f0.w),
                   pkbf(f1.x, f1.y), pkbf(f1.z, f1.w)};
        afr[ks] = __builtin_bit_cast(bf16x8, a);
    }

    // acc[n][r] = qkv[token = quad*4+r][n*16+col]; init = bias splat
    f32x4 acc[24];
#pragma unroll
    for (int n = 0; n < 24; ++n) {
        float b = bqkv[n * 16 + col];
        acc[n] = (f32x4){b, b, b, b};
    }
#pragma unroll
    for (int ks = 0; ks < 4; ++ks) {
#pragma unroll
        for (int g = 0; g < 4; ++g) {
            bf16x8 bfr[6];             // 6 weight loads in flight per group
#pragma unroll
            for (int j = 0; j < 6; ++j)
                bfr[j] = *(const bf16x8*)&wqkvT[((g * 6 + j) * 16 + col) * 128 + ks * 32 + quad * 8];
#pragma unroll
            for (int j = 0; j < 6; ++j)
                acc[g * 6 + j] = __builtin_amdgcn_mfma_f32_16x16x32_bf16(
                    afr[ks], bfr[j], acc[g * 6 + j], 0, 0, 0);
        }
    }

    // ---- transpose: qkv -> wave-private LDS bf16 [tok16][ch]; NO barrier —
    // reads below are same-wave, compiler inserts lgkmcnt waits.
#pragma unroll
    for (int n = 0; n < 24; ++n)
#pragma unroll
        for (int r = 0; r < 4; ++r)
            uw[(quad * 4 + r) * QKV_STRIDE + n * 16 + col] = f2bf(acc[n][r]);

    // ---- stage B: 2 pairs per lane: t16 = (lane>>3) + 8p, h = lane&7
    const float sl2e = 0.08838834764831845f * 1.44269504088896340f; // scale*log2(e)
#pragma unroll
    for (int p = 0; p < 2; ++p) {
        const int t16 = (lane >> 3) + 8 * p;
        const int h   = lane & 7;
        const unsigned short* row = uw + t16 * QKV_STRIDE + h * 16;

        u32x4 qp0 = *(const u32x4*)(row);
        u32x4 qp1 = *(const u32x4*)(row + 8);
        u32x4 kp0 = *(const u32x4*)(row + 128);
        u32x4 kp1 = *(const u32x4*)(row + 136);
        u32x4 vp0 = *(const u32x4*)(row + 256);
        u32x4 vp1 = *(const u32x4*)(row + 264);

        float qv[16], kf[16], vf[16];
#pragma unroll
        for (int c = 0; c < 4; ++c) {
            qv[2*c]   = bflo(qp0[c]); qv[2*c+1]   = bfhi(qp0[c]);
            qv[8+2*c] = bflo(qp1[c]); qv[8+2*c+1] = bfhi(qp1[c]);
            kf[2*c]   = bflo(kp0[c]); kf[2*c+1]   = bfhi(kp0[c]);
            kf[8+2*c] = bflo(kp1[c]); kf[8+2*c+1] = bfhi(kp1[c]);
            vf[2*c]   = bflo(vp0[c]); vf[2*c+1]   = bfhi(vp0[c]);
            vf[8+2*c] = bflo(vp1[c]); vf[8+2*c+1] = bfhi(vp1[c]);
        }
        float ov[16];
#pragma unroll
        for (int i = 0; i < 16; ++i) {
            float qs = qv[i] * sl2e;
            float den = 0.f, num = 0.f;
#pragma unroll
            for (int j = 0; j < 16; ++j) {
                float e = __builtin_amdgcn_exp2f(qs * kf[j]);
                den += e;
                num = fmaf(e, vf[j], num);
            }
            ov[i] = num * __builtin_amdgcn_rcpf(den);
        }
        // pack o -> bf16, store to global: row t byte t*512, head h at +h*32
        u32x4 o0 = {pkbf(ov[0], ov[1]), pkbf(ov[2], ov[3]), pkbf(ov[4], ov[5]), pkbf(ov[6], ov[7])};
        u32x4 o1 = {pkbf(ov[8], ov[9]), pkbf(ov[10], ov[11]), pkbf(ov[12], ov[13]), pkbf(ov[14], ov[15])};
        char* orow = obuf + (size_t)(wbase + t16) * 512 + h * 32;
        *(u32x4*)(orow)      = o0;
        *(u32x4*)(orow + 16) = o1;
    }
}

// ---------------- kernel 2: streaming proj GEMM (unchanged from R6) --------
__global__ __launch_bounds__(256) void proj_gemm(
    const char* __restrict__ obuf,     // bf16 o: row t at byte t*512, 256 B
    const unsigned short* __restrict__ wprojT,
    const float* __restrict__ bproj,
    float* __restrict__ out)
{
    __shared__ __align__(16) unsigned short os[PTILE * O_STRIDE];  // 17408 B

    const int tid  = threadIdx.x;
    const int lane = tid & 63;
    const int wave = tid >> 6;
    const int col  = lane & 15;
    const int quad = lane >> 4;
    const long base = (long)blockIdx.x * PTILE;

    // ---- stage o tile: 64 rows x 256 B -> LDS stride 136 (coalesced reads)
#pragma unroll
    for (int i = 0; i < 4; ++i) {
        int q = tid + 256 * i;          // 0..1023 16B chunks
        int r = q >> 4, c = q & 15;
        u32x4 v = *(const u32x4*)(obuf + (size_t)(base + r) * 512 + c * 16);
        *(u32x4*)&os[r * O_STRIDE + c * 8] = v;
    }
    __syncthreads();

    // ---- wave: m-tile = wave, all 8 n-tiles
    bf16x8 af[4];
#pragma unroll
    for (int ks = 0; ks < 4; ++ks)
        af[ks] = *(const bf16x8*)&os[(wave * 16 + col) * O_STRIDE + ks * 32 + quad * 8];

    f32x4 acc[8];
#pragma unroll
    for (int n = 0; n < 8; ++n) {
        float b = bproj[n * 16 + col];
        acc[n] = (f32x4){b, b, b, b};
    }
#pragma unroll
    for (int ks = 0; ks < 4; ++ks) {
#pragma unroll
        for (int half = 0; half < 2; ++half) {
            bf16x8 bb[4];
#pragma unroll
            for (int n = 0; n < 4; ++n)
                bb[n] = *(const bf16x8*)&wprojT[((half * 4 + n) * 16 + col) * 128 + ks * 32 + quad * 8];
#pragma unroll
            for (int n = 0; n < 4; ++n)
                acc[half * 4 + n] = __builtin_amdgcn_mfma_f32_16x16x32_bf16(
                    af[ks], bb[n], acc[half * 4 + n], 0, 0, 0);
        }
    }
    // epilogue: fp32 store (overwrites the staged o region of THIS block only)
#pragma unroll
    for (int n = 0; n < 8; ++n)
#pragma unroll
        for (int r = 0; r < 4; ++r) {
            long tt = base + wave * 16 + quad * 4 + r;
            out[tt * 128 + n * 16 + col] = acc[n][r];
        }
}

extern "C" void kernel_launch(void* const* d_in, const int* in_sizes, int n_in,
                              void* d_out, int out_size, void* d_ws, size_t ws_size,
                              hipStream_t stream) {
    const float* x     = (const float*)d_in[0];
    const float* wqkv  = (const float*)d_in[1];
    const float* bqkv  = (const float*)d_in[2];
    const float* wproj = (const float*)d_in[3];
    const float* bproj = (const float*)d_in[4];
    float* out = (float*)d_out;

    unsigned short* wqkvT  = (unsigned short*)d_ws;    // 384*128 bf16
    unsigned short* wprojT = wqkvT + 384 * 128;        // 128*128 bf16

    prep_weights<<<192, 256, 0, stream>>>(wqkv, wproj, wqkvT, wprojT);

    const int tokens = in_sizes[0] / 128;              // 65536
    qkv_attn<<<tokens / 64, 256, 0, stream>>>(
        x, wqkvT, bqkv, (char*)d_out);
    proj_gemm<<<tokens / PTILE, 256, 0, stream>>>(
        (const char*)d_out, wprojT, bproj, out);
}

// Round 9
// 166.358 us; speedup vs baseline: 1.0069x; 1.0069x over previous
//
#include <hip/hip_runtime.h>

// ChannelAttention for MI355X (gfx950), round 8.
// B=4, L=16384, C=128, H=8, hd=16. Tokens M = 65536.
//
// R8 vs R7: R6 vs R7 proved LDS size (resident waves), not barriers, sets the
// time (pure latency-bound: dur ~ 1/VALUBusy ~ 1/occupancy). So: 128-thread
// blocks, 16-token subtiles, LDS = 2 x 12.5 KB ping-pong (25 KB total) ->
// ~16 waves/CU cap; plus an intra-block software pipeline: subtile-1's x
// loads issue before the barrier and drain under subtile-0's attention phase.
//   k1 qkv_attn: per subtile: qkv = x@Wqkv+b (MFMA, wave owns 12 n-tiles) ->
//      LDS transpose -> barrier -> per-(token,head) fp32 softmax-attention ->
//      bf16 o to global (inside d_out: first 256 B of each 512 B fp32 row).
//   k2 proj: out = o@Wproj+b streaming GEMM (unchanged, near HBM floor).
// Weights pre-transposed+bf16 in d_ws ([N][K] -> B-frags are 16B loads).

typedef __attribute__((ext_vector_type(8))) short bf16x8;
typedef __attribute__((ext_vector_type(4))) float f32x4;
typedef __attribute__((ext_vector_type(4))) unsigned int u32x4;

#define QKV_STRIDE 392   // bf16 elems per LDS token row (>=384); 784B, 16B aligned
#define SUB_LDS (16 * QKV_STRIDE)    // per-subtile buffer: 12544 B
#define PTILE 64         // k2 tokens per block
#define O_STRIDE 136     // k2 LDS row stride (bf16 elems)

__device__ __forceinline__ unsigned short f2bf(float f) {
    unsigned int u = __builtin_bit_cast(unsigned int, f);
    u += 0x8000u;                      // round half up
    return (unsigned short)(u >> 16);
}
// pack two floats -> packed bf16x2 (lo in low short) in 3 VALU ops
__device__ __forceinline__ unsigned int pkbf(float lo, float hi) {
    unsigned int a = __builtin_bit_cast(unsigned int, lo) + 0x8000u;
    unsigned int b = __builtin_bit_cast(unsigned int, hi) + 0x8000u;
    return __builtin_amdgcn_perm(b, a, 0x07060302u);  // {hi16(b),hi16(a)}
}
__device__ __forceinline__ float bflo(unsigned int u) {
    return __builtin_bit_cast(float, u << 16);
}
__device__ __forceinline__ float bfhi(unsigned int u) {
    return __builtin_bit_cast(float, u & 0xffff0000u);
}

__global__ void prep_weights(const float* __restrict__ wqkv,
                             const float* __restrict__ wproj,
                             unsigned short* __restrict__ wqkvT,
                             unsigned short* __restrict__ wprojT) {
    int idx = blockIdx.x * 256 + threadIdx.x;
    if (idx < 384 * 128) {               // wqkvT[n][k] = bf16(wqkv[k][n])
        int n = idx >> 7, k = idx & 127;
        wqkvT[idx] = f2bf(wqkv[k * 384 + n]);
    }
    if (idx < 128 * 128) {               // wprojT[n][k] = bf16(wproj[k][n])
        int n = idx >> 7, k = idx & 127;
        wprojT[idx] = f2bf(wproj[k * 128 + n]);
    }
}

// stage B: per-(token,head) fp32 attention from LDS buf, o -> global bf16
__device__ __forceinline__ void stage_b(const unsigned short* __restrict__ buf,
                                        long tokbase, int tid,
                                        char* __restrict__ obuf) {
    const int t = tid >> 3;            // 0..15
    const int h = tid & 7;             // 0..7
    const unsigned short* row = buf + t * QKV_STRIDE + h * 16;

    u32x4 qp0 = *(const u32x4*)(row);
    u32x4 qp1 = *(const u32x4*)(row + 8);
    u32x4 kp0 = *(const u32x4*)(row + 128);
    u32x4 kp1 = *(const u32x4*)(row + 136);
    u32x4 vp0 = *(const u32x4*)(row + 256);
    u32x4 vp1 = *(const u32x4*)(row + 264);

    const float sl2e = 0.08838834764831845f * 1.44269504088896340f; // scale*log2(e)
    float qv[16], kf[16], vf[16];
#pragma unroll
    for (int c = 0; c < 4; ++c) {
        qv[2*c]   = bflo(qp0[c]); qv[2*c+1]   = bfhi(qp0[c]);
        qv[8+2*c] = bflo(qp1[c]); qv[8+2*c+1] = bfhi(qp1[c]);
        kf[2*c]   = bflo(kp0[c]); kf[2*c+1]   = bfhi(kp0[c]);
        kf[8+2*c] = bflo(kp1[c]); kf[8+2*c+1] = bfhi(kp1[c]);
        vf[2*c]   = bflo(vp0[c]); vf[2*c+1]   = bfhi(vp0[c]);
        vf[8+2*c] = bflo(vp1[c]); vf[8+2*c+1] = bfhi(vp1[c]);
    }
    float ov[16];
#pragma unroll
    for (int i = 0; i < 16; ++i) {
        float qs = qv[i] * sl2e;
        // two independent partial chains: halves exp->add serialization
        float d0 = 0.f, d1 = 0.f, n0 = 0.f, n1 = 0.f;
#pragma unroll
        for (int j = 0; j < 16; j += 2) {
            float e0 = __builtin_amdgcn_exp2f(qs * kf[j]);
            float e1 = __builtin_amdgcn_exp2f(qs * kf[j + 1]);
            d0 += e0; d1 += e1;
            n0 = fmaf(e0, vf[j], n0);
            n1 = fmaf(e1, vf[j + 1], n1);
        }
        ov[i] = (n0 + n1) * __builtin_amdgcn_rcpf(d0 + d1);
    }
    u32x4 o0 = {pkbf(ov[0], ov[1]), pkbf(ov[2], ov[3]), pkbf(ov[4], ov[5]), pkbf(ov[6], ov[7])};
    u32x4 o1 = {pkbf(ov[8], ov[9]), pkbf(ov[10], ov[11]), pkbf(ov[12], ov[13]), pkbf(ov[14], ov[15])};
    char* orow = obuf + (size_t)(tokbase + t) * 512 + h * 32;
    *(u32x4*)(orow)      = o0;
    *(u32x4*)(orow + 16) = o1;
}

// ---------------- kernel 1: qkv GEMM + channel attention, pipelined --------
__global__ __launch_bounds__(128, 4) void qkv_attn(
    const float* __restrict__ x,
    const unsigned short* __restrict__ wqkvT,
    const float* __restrict__ bqkv,
    char* __restrict__ obuf)          // = (char*)d_out; o row t at byte t*512
{
    __shared__ __align__(16) unsigned short us[2 * SUB_LDS];  // 25088 B

    const int tid  = threadIdx.x;
    const int lane = tid & 63;
    const int wave = tid >> 6;        // 0..1
    const int col  = lane & 15;       // MFMA C/D col == A row (m) == B col (n)
    const int quad = lane >> 4;
    const long base = (long)blockIdx.x * 32;  // 2 subtiles x 16 tokens
    const int nb = wave * 12;         // this wave's 12 n-tiles

    // bias splat (reused by both subtiles)
    float bias[12];
#pragma unroll
    for (int j = 0; j < 12; ++j) bias[j] = bqkv[(nb + j) * 16 + col];

    // ---- subtile 0: x loads
    const float* xrow0 = x + (base + col) * 128;
    float4 s0[4][2];
#pragma unroll
    for (int ks = 0; ks < 4; ++ks) {
        const float4* p = (const float4*)(xrow0 + ks * 32 + quad * 8);
        s0[ks][0] = p[0];
        s0[ks][1] = p[1];
    }
    bf16x8 afr[4];
#pragma unroll
    for (int ks = 0; ks < 4; ++ks) {
        float4 f0 = s0[ks][0], f1 = s0[ks][1];
        u32x4 a = {pkbf(f0.x, f0.y), pkbf(f0.z, f0.w),
                   pkbf(f1.x, f1.y), pkbf(f1.z, f1.w)};
        afr[ks] = __builtin_bit_cast(bf16x8, a);
    }

    // ---- subtile 0: qkv MFMA (wave: 12 n-tiles x 1 m-tile)
    f32x4 acc[12];
#pragma unroll
    for (int j = 0; j < 12; ++j) acc[j] = (f32x4){bias[j], bias[j], bias[j], bias[j]};
#pragma unroll
    for (int ks = 0; ks < 4; ++ks) {
#pragma unroll
        for (int g = 0; g < 2; ++g) {
            bf16x8 bfr[6];             // 6 weight loads in flight
#pragma unroll
            for (int j = 0; j < 6; ++j)
                bfr[j] = *(const bf16x8*)&wqkvT[((nb + g * 6 + j) * 16 + col) * 128 + ks * 32 + quad * 8];
#pragma unroll
            for (int j = 0; j < 6; ++j)
                acc[g * 6 + j] = __builtin_amdgcn_mfma_f32_16x16x32_bf16(
                    afr[ks], bfr[j], acc[g * 6 + j], 0, 0, 0);
        }
    }
    // transpose -> buf0
#pragma unroll
    for (int j = 0; j < 12; ++j)
#pragma unroll
        for (int r = 0; r < 4; ++r)
            us[(quad * 4 + r) * QKV_STRIDE + (nb + j) * 16 + col] = f2bf(acc[j][r]);

    // ---- subtile 1: x loads ISSUED NOW, drain under stage B0 + barrier
    const float* xrow1 = x + (base + 16 + col) * 128;
    float4 s1[4][2];
#pragma unroll
    for (int ks = 0; ks < 4; ++ks) {
        const float4* p = (const float4*)(xrow1 + ks * 32 + quad * 8);
        s1[ks][0] = p[0];
        s1[ks][1] = p[1];
    }

    __syncthreads();   // buf0 complete

    // ---- stage B for subtile 0 (long VALU/trans phase; x1 in flight)
    stage_b(us, base, tid, obuf);

    // ---- subtile 1: pack (x1 arrived during stage B0), MFMA, transpose
#pragma unroll
    for (int ks = 0; ks < 4; ++ks) {
        float4 f0 = s1[ks][0], f1 = s1[ks][1];
        u32x4 a = {pkbf(f0.x, f0.y), pkbf(f0.z, f0.w),
                   pkbf(f1.x, f1.y), pkbf(f1.z, f1.w)};
        afr[ks] = __builtin_bit_cast(bf16x8, a);
    }
#pragma unroll
    for (int j = 0; j < 12; ++j) acc[j] = (f32x4){bias[j], bias[j], bias[j], bias[j]};
#pragma unroll
    for (int ks = 0; ks < 4; ++ks) {
#pragma unroll
        for (int g = 0; g < 2; ++g) {
            bf16x8 bfr[6];
#pragma unroll
            for (int j = 0; j < 6; ++j)
                bfr[j] = *(const bf16x8*)&wqkvT[((nb + g * 6 + j) * 16 + col) * 128 + ks * 32 + quad * 8];
#pragma unroll
            for (int j = 0; j < 6; ++j)
                acc[g * 6 + j] = __builtin_amdgcn_mfma_f32_16x16x32_bf16(
                    afr[ks], bfr[j], acc[g * 6 + j], 0, 0, 0);
        }
    }
#pragma unroll
    for (int j = 0; j < 12; ++j)
#pragma unroll
        for (int r = 0; r < 4; ++r)
            us[SUB_LDS + (quad * 4 + r) * QKV_STRIDE + (nb + j) * 16 + col] = f2bf(acc[j][r]);

    __syncthreads();   // buf1 complete

    // ---- stage B for subtile 1
    stage_b(us + SUB_LDS, base + 16, tid, obuf);
}

// ---------------- kernel 2: streaming proj GEMM (unchanged) ----------------
__global__ __launch_bounds__(256) void proj_gemm(
    const char* __restrict__ obuf,     // bf16 o: row t at byte t*512, 256 B
    const unsigned short* __restrict__ wprojT,
    const float* __restrict__ bproj,
    float* __restrict__ out)
{
    __shared__ __align__(16) unsigned short os[PTILE * O_STRIDE];  // 17408 B

    const int tid  = threadIdx.x;
    const int lane = tid & 63;
    const int wave = tid >> 6;
    const int col  = lane & 15;
    const int quad = lane >> 4;
    const long base = (long)blockIdx.x * PTILE;

    // ---- stage o tile: 64 rows x 256 B -> LDS stride 136 (coalesced reads)
#pragma unroll
    for (int i = 0; i < 4; ++i) {
        int q = tid + 256 * i;          // 0..1023 16B chunks
        int r = q >> 4, c = q & 15;
        u32x4 v = *(const u32x4*)(obuf + (size_t)(base + r) * 512 + c * 16);
        *(u32x4*)&os[r * O_STRIDE + c * 8] = v;
    }
    __syncthreads();

    // ---- wave: m-tile = wave, all 8 n-tiles
    bf16x8 af[4];
#pragma unroll
    for (int ks = 0; ks < 4; ++ks)
        af[ks] = *(const bf16x8*)&os[(wave * 16 + col) * O_STRIDE + ks * 32 + quad * 8];

    f32x4 acc[8];
#pragma unroll
    for (int n = 0; n < 8; ++n) {
        float b = bproj[n * 16 + col];
        acc[n] = (f32x4){b, b, b, b};
    }
#pragma unroll
    for (int ks = 0; ks < 4; ++ks) {
#pragma unroll
        for (int half = 0; half < 2; ++half) {
            bf16x8 bb[4];
#pragma unroll
            for (int n = 0; n < 4; ++n)
                bb[n] = *(const bf16x8*)&wprojT[((half * 4 + n) * 16 + col) * 128 + ks * 32 + quad * 8];
#pragma unroll
            for (int n = 0; n < 4; ++n)
                acc[half * 4 + n] = __builtin_amdgcn_mfma_f32_16x16x32_bf16(
                    af[ks], bb[n], acc[half * 4 + n], 0, 0, 0);
        }
    }
    // epilogue: fp32 store (overwrites the staged o region of THIS block only)
#pragma unroll
    for (int n = 0; n < 8; ++n)
#pragma unroll
        for (int r = 0; r < 4; ++r) {
            long tt = base + wave * 16 + quad * 4 + r;
            out[tt * 128 + n * 16 + col] = acc[n][r];
        }
}

extern "C" void kernel_launch(void* const* d_in, const int* in_sizes, int n_in,
                              void* d_out, int out_size, void* d_ws, size_t ws_size,
                              hipStream_t stream) {
    const float* x     = (const float*)d_in[0];
    const float* wqkv  = (const float*)d_in[1];
    const float* bqkv  = (const float*)d_in[2];
    const float* wproj = (const float*)d_in[3];
    const float* bproj = (const float*)d_in[4];
    float* out = (float*)d_out;

    unsigned short* wqkvT  = (unsigned short*)d_ws;    // 384*128 bf16
    unsigned short* wprojT = wqkvT + 384 * 128;        // 128*128 bf16

    prep_weights<<<192, 256, 0, stream>>>(wqkv, wproj, wqkvT, wprojT);

    const int tokens = in_sizes[0] / 128;              // 65536
    qkv_attn<<<tokens / 32, 128, 0, stream>>>(
        x, wqkvT, bqkv, (char*)d_out);
    proj_gemm<<<tokens / PTILE, 256, 0, stream>>>(
        (const char*)d_out, wprojT, bproj, out);
}